// Round 4
// baseline (332.804 us; speedup 1.0000x reference)
//
#include <hip/hip_runtime.h>
#include <hip/hip_bf16.h>
#include <stdint.h>

#define TSTEPS 4

typedef __bf16 bf16_t;
typedef __attribute__((ext_vector_type(8))) __bf16 bf16x8;
typedef __attribute__((ext_vector_type(16))) float f32x16;
typedef __attribute__((ext_vector_type(4))) unsigned short ushort4v;

union frag_u { bf16x8 v; uint32_t d[4]; unsigned short u[8]; };

// gfx9 s_waitcnt immediates: vmcnt low4 [3:0] hi2 [15:14]; expcnt=7,lgkm=15 off
#define VMCNT8  0xF78
#define VMCNT0  0xF70

// ---------------------------------------------------------------------------
// R20: wave tile widened 32x32 -> 32x64 (two n-blocks, acc0/acc1).
// Rationale: at full MFMA rate the old tile needed 63 B/cyc/CU of fragment
// return (8 lines/MFMA) = the measured L2-return ceiling; MfmaUtil plateaued
// at 46-50%. New tile: A-frags + perms reused across 2 n-blocks -> 375 B and
// 6 lines per MFMA, and the per-step MFMA burst doubles to 512 per-SIMD cyc
// (better latency tolerance, half the loop overhead). Depth-2 prefetch.
// Spike bytes remain 0x3F -> v_perm to high byte = bf16 0.5; B pre-doubled
// (2*hi / 2*lo) so products are bitwise-identical to 1.0*w (R19-proven).
// A layout: [m_blk32][kb16][t][row0..31][16 bytes], byte = 0x00 / 0x3F.
// B-frag layout: packet ((n>>5)*NKB + (k>>4))*512 + ((n&31)+32*((k>>3)&1))*8
// + (k&7), bf16, value = 2*w_hi / 2*w_lo.
// ---------------------------------------------------------------------------

// ---------------------------------------------------------------------------
// Stage 1: input LIF encoder -> spike 0x3F bytes. C=128. XLA-exact LIF.
// ---------------------------------------------------------------------------
__global__ void spike_encode_i8(const float* __restrict__ x,
                                uint4* __restrict__ s1)
{
    const int C = 128;
    int tid = blockIdx.x * blockDim.x + threadIdx.x;  // 65536 = 256*8*32
    int row = tid & 31;
    int kb  = (tid >> 5) & 7;
    int m_blk = tid >> 8;
    int m = m_blk * 32 + row;
    const float* px = x + (size_t)m * C + kb * 16;
    float xv[16];
#pragma unroll
    for (int j = 0; j < 16; j += 4) {
        float4 t4 = *(const float4*)(px + j);
        xv[j] = t4.x; xv[j+1] = t4.y; xv[j+2] = t4.z; xv[j+3] = t4.w;
    }
    float v[16];
#pragma unroll
    for (int j = 0; j < 16; ++j) v[j] = 0.0f;
#pragma unroll
    for (int t = 0; t < TSTEPS; ++t) {
        uint32_t dw[4] = {0u, 0u, 0u, 0u};
#pragma unroll
        for (int j = 0; j < 16; ++j) {
            float vv = __fadd_rn(v[j], __fmul_rn(__fsub_rn(xv[j], v[j]), 0.5f));
            bool sp = (vv >= 1.0f);
            dw[j >> 2] |= sp ? (0x3Fu << ((j & 3) * 8)) : 0u;
            v[j] = sp ? 0.0f : vv;
        }
        uint4 o; o.x = dw[0]; o.y = dw[1]; o.z = dw[2]; o.w = dw[3];
        s1[((size_t)(m_blk * 8 + kb) * 4 + t) * 32 + row] = o;
    }
}

// ---------------------------------------------------------------------------
// Weight prep: W [K][N] fp32 -> 2*hi / 2*lo bf16 split in B-frag layout.
// hi/lo rounding UNCHANGED; doubling applied to the already-rounded bf16
// values (exact exponent increment, no re-rounding).
// ---------------------------------------------------------------------------
__global__ void split_transpose_all(const float* __restrict__ enc_W,
                                    const float* __restrict__ W_cells,
                                    bf16_t* __restrict__ W1h, bf16_t* __restrict__ W1l,
                                    bf16_t* __restrict__ W2h, bf16_t* __restrict__ W2l,
                                    bf16_t* __restrict__ W3h, bf16_t* __restrict__ W3l)
{
    const int N = 1024;
    const float* W;
    bf16_t *hi, *lo;
    int K;
    if (blockIdx.z == 0) {
        if (blockIdx.x >= 4) return;
        W = enc_W; hi = W1h; lo = W1l; K = 128;
    } else if (blockIdx.z == 1) {
        W = W_cells; hi = W2h; lo = W2l; K = 1024;
    } else {
        W = W_cells + (size_t)1024 * 1024; hi = W3h; lo = W3l; K = 1024;
    }
    const int NKB = K >> 4;
    __shared__ float tile[32][33];
    int k0 = blockIdx.x * 32, n0 = blockIdx.y * 32;
    int tx = threadIdx.x & 31, ty = threadIdx.x >> 5;
    for (int kk = ty; kk < 32; kk += 8)
        tile[kk][tx] = W[(size_t)(k0 + kk) * N + n0 + tx];
    __syncthreads();

    const int nn = tx;
    const int oc = ty;            // 0..7
    const int o2 = oc & 3;        // k-octet
    const bool isLo = (oc >> 2) != 0;
    const int kblk = (k0 >> 4) + (o2 >> 1);
    const int lane_in_packet = nn + 32 * (o2 & 1);

    frag_u f;
#pragma unroll
    for (int j = 0; j < 8; ++j) {
        float wv = tile[o2 * 8 + j][nn];
        bf16_t h = (bf16_t)wv;                          // original hi rounding
        bf16_t l = (bf16_t)(wv - (float)h);             // original lo rounding
        f.v[j] = isLo ? (bf16_t)(2.0f * (float)l)       // exact doubling
                      : (bf16_t)(2.0f * (float)h);
    }
    bf16_t* dst = (isLo ? lo : hi)
        + ((size_t)((n0 + nn) >> 5) * NKB + kblk) * 512 + lane_in_packet * 8;
    *(bf16x8*)dst = f.v;
}

// ---------------------------------------------------------------------------
// Fused MFMA GEMM + multistep LIF. R20: 32x64 wave tile (A-frag reuse across
// two n-blocks), depth-2 prefetch (vmcnt(8)), XCD-locality swizzle,
// 2 blocks/CU.
// ---------------------------------------------------------------------------
template <int K, bool LAST>
__global__ __launch_bounds__(256, 2)
void gemm_lif_mfma(const uint8_t* __restrict__ Abytes,
                   const bf16_t* __restrict__ Bh,
                   const bf16_t* __restrict__ Bl,
                   const float* __restrict__ bias,
                   uint8_t* __restrict__ Sbytes,
                   float* __restrict__ Out,
                   int M, int N)
{
    constexpr int NKB = K >> 4;                 // 8 or 64 (even)
    __shared__ __align__(8) unsigned short sh[4][256];   // [wave][row][kb][t]

    const int tid = threadIdx.x;
    const int lane = tid & 63;
    const int wid = tid >> 6;
    const int l31 = lane & 31;
    const int half = lane >> 5;

    // XCD-locality swizzle: 1024 blocks (block tile 64m x 128n), default
    // XCD = bid & 7. XCD x owns m_t in [x*16, x*16+16). Walk
    // nh(2) x mloc(16) x n4(4): hot set = 4 B-panels (2MB) + A-tile (256KB)
    // < 4MB per-XCD L2. Bijective.
    const int bid = blockIdx.x;
    const int xcd = bid & 7;
    const int j   = bid >> 3;                   // 0..127
    const int nh   = j >> 6;                    // 0..1
    const int r    = j & 63;
    const int mloc = r >> 2;                    // 0..15
    const int n_t  = nh * 4 + (r & 3);          // 0..7
    const int m_t  = xcd * 16 + mloc;           // 0..127

    const int m0 = m_t * 64, n0 = n_t * 128;
    const int wave_m = (wid & 1) * 32;
    const int wave_n = (wid >> 1) * 64;         // 0 or 64
    const int m_blk = (m0 + wave_m) >> 5;
    const int n_blk = (n0 + wave_n) >> 5;       // first of the wave's 2

    const uint8_t* pA = Abytes + (size_t)m_blk * NKB * 4 * 512 + l31 * 16 + half * 8;
    const bf16_t* pH0 = Bh + (size_t)n_blk * NKB * 512 + lane * 8;
    const bf16_t* pL0 = Bl + (size_t)n_blk * NKB * 512 + lane * 8;
    const bf16_t* pH1 = pH0 + (size_t)NKB * 512;
    const bf16_t* pL1 = pL0 + (size_t)NKB * 512;

    f32x16 acc0[TSTEPS], acc1[TSTEPS];
#pragma unroll
    for (int t = 0; t < TSTEPS; ++t)
        for (int rr = 0; rr < 16; ++rr) { acc0[t][rr] = 0.0f; acc1[t][rr] = 0.0f; }

    uint2 fm[2][4];
    bf16x8 fh0[2], fl0[2], fh1[2], fl1[2];

#define LOADB(kb_, s_) {                                                     \
        fm[s_][0] = *(const uint2*)(pA + ((size_t)(kb_) * 4 + 0) * 512);     \
        fm[s_][1] = *(const uint2*)(pA + ((size_t)(kb_) * 4 + 1) * 512);     \
        fm[s_][2] = *(const uint2*)(pA + ((size_t)(kb_) * 4 + 2) * 512);     \
        fm[s_][3] = *(const uint2*)(pA + ((size_t)(kb_) * 4 + 3) * 512);     \
        fh0[s_] = *(const bf16x8*)(pH0 + (kb_) * 512);                       \
        fl0[s_] = *(const bf16x8*)(pL0 + (kb_) * 512);                       \
        fh1[s_] = *(const bf16x8*)(pH1 + (kb_) * 512);                       \
        fl1[s_] = *(const bf16x8*)(pL1 + (kb_) * 512);                       \
    }

// byte 0x3F -> high byte of each 16-bit half = 0x3F00 = bf16 0.5 (1 perm/dw)
#define EXPANDF(a_, f_) {                                                    \
        (f_).d[0] = __builtin_amdgcn_perm((a_).x, 0u, 0x05000400u);          \
        (f_).d[1] = __builtin_amdgcn_perm((a_).x, 0u, 0x07000600u);          \
        (f_).d[2] = __builtin_amdgcn_perm((a_).y, 0u, 0x05000400u);          \
        (f_).d[3] = __builtin_amdgcn_perm((a_).y, 0u, 0x07000600u);          \
    }

#define MFMASTEP(s_) {                                                       \
        frag_u af0, af1, af2, af3;                                           \
        EXPANDF(fm[s_][0], af0);                                             \
        EXPANDF(fm[s_][1], af1);                                             \
        EXPANDF(fm[s_][2], af2);                                             \
        EXPANDF(fm[s_][3], af3);                                             \
        acc0[0] = __builtin_amdgcn_mfma_f32_32x32x16_bf16(af0.v, fh0[s_], acc0[0], 0, 0, 0); \
        acc1[0] = __builtin_amdgcn_mfma_f32_32x32x16_bf16(af0.v, fh1[s_], acc1[0], 0, 0, 0); \
        acc0[1] = __builtin_amdgcn_mfma_f32_32x32x16_bf16(af1.v, fh0[s_], acc0[1], 0, 0, 0); \
        acc1[1] = __builtin_amdgcn_mfma_f32_32x32x16_bf16(af1.v, fh1[s_], acc1[1], 0, 0, 0); \
        acc0[2] = __builtin_amdgcn_mfma_f32_32x32x16_bf16(af2.v, fh0[s_], acc0[2], 0, 0, 0); \
        acc1[2] = __builtin_amdgcn_mfma_f32_32x32x16_bf16(af2.v, fh1[s_], acc1[2], 0, 0, 0); \
        acc0[3] = __builtin_amdgcn_mfma_f32_32x32x16_bf16(af3.v, fh0[s_], acc0[3], 0, 0, 0); \
        acc1[3] = __builtin_amdgcn_mfma_f32_32x32x16_bf16(af3.v, fh1[s_], acc1[3], 0, 0, 0); \
        acc0[0] = __builtin_amdgcn_mfma_f32_32x32x16_bf16(af0.v, fl0[s_], acc0[0], 0, 0, 0); \
        acc1[0] = __builtin_amdgcn_mfma_f32_32x32x16_bf16(af0.v, fl1[s_], acc1[0], 0, 0, 0); \
        acc0[1] = __builtin_amdgcn_mfma_f32_32x32x16_bf16(af1.v, fl0[s_], acc0[1], 0, 0, 0); \
        acc1[1] = __builtin_amdgcn_mfma_f32_32x32x16_bf16(af1.v, fl1[s_], acc1[1], 0, 0, 0); \
        acc0[2] = __builtin_amdgcn_mfma_f32_32x32x16_bf16(af2.v, fl0[s_], acc0[2], 0, 0, 0); \
        acc1[2] = __builtin_amdgcn_mfma_f32_32x32x16_bf16(af2.v, fl1[s_], acc1[2], 0, 0, 0); \
        acc0[3] = __builtin_amdgcn_mfma_f32_32x32x16_bf16(af3.v, fl0[s_], acc0[3], 0, 0, 0); \
        acc1[3] = __builtin_amdgcn_mfma_f32_32x32x16_bf16(af3.v, fl1[s_], acc1[3], 0, 0, 0); \
    }

    LOADB(0, 0);
    for (int kb = 0; kb < NKB - 2; kb += 2) {
        LOADB(kb + 1, 1);
        __builtin_amdgcn_s_waitcnt(VMCNT8);
        asm volatile("" ::: "memory");
        MFMASTEP(0);
        LOADB(kb + 2, 0);
        __builtin_amdgcn_s_waitcnt(VMCNT8);
        asm volatile("" ::: "memory");
        MFMASTEP(1);
    }
    LOADB(NKB - 1, 1);
    __builtin_amdgcn_s_waitcnt(VMCNT8);
    asm volatile("" ::: "memory");
    MFMASTEP(0);
    __builtin_amdgcn_s_waitcnt(VMCNT0);
    asm volatile("" ::: "memory");
    MFMASTEP(1);

#undef MFMASTEP
#undef EXPANDF
#undef LOADB

    // --- LIF epilogue: t-scan in registers (XLA-exact), run per n-block ---
    unsigned short* myt = &sh[wid][0];          // [row][kb][t] = [32][2][4]
    const int NKBo = N >> 4;

#define EPILOG(acc_, nidx_) {                                                \
        const float bv = bias[n0 + wave_n + (nidx_) * 32 + l31];             \
        f32x16 vmem;                                                         \
        _Pragma("unroll")                                                    \
        for (int rr = 0; rr < 16; ++rr) vmem[rr] = 0.0f;                     \
        uint64_t bits = 0ull;                                                \
        for (int t = 0; t < TSTEPS; ++t) {                                   \
            _Pragma("unroll")                                                \
            for (int rr = 0; rr < 16; ++rr) {                                \
                float y = __fadd_rn(acc_[t][rr], bv);                        \
                float vv = vmem[rr];                                         \
                vv = __fadd_rn(vv, __fmul_rn(__fsub_rn(y, vv), 0.5f));       \
                bool sp = (vv >= 1.0f);                                      \
                vmem[rr] = sp ? 0.0f : vv;                                   \
                if (LAST) {                                                  \
                    bits |= sp ? (1ull << (rr * 4 + t)) : 0ull;              \
                } else {                                                     \
                    unsigned long long b = __ballot(sp);                     \
                    if (l31 == 0) {                                          \
                        uint32_t hb = (uint32_t)(b >> (half * 32));          \
                        int rowi = (rr & 3) + 8 * (rr >> 2) + 4 * half;      \
                        myt[(rowi * 2 + 0) * 4 + t] = (unsigned short)hb;    \
                        myt[(rowi * 2 + 1) * 4 + t] = (unsigned short)(hb >> 16); \
                    }                                                        \
                }                                                            \
            }                                                                \
        }                                                                    \
        if (LAST) {                                                          \
            _Pragma("unroll")                                                \
            for (int rr = 0; rr < 16; ++rr) {                                \
                int m_r = (rr & 3) + 8 * (rr >> 2) + 4 * half;               \
                int m = m0 + wave_m + m_r;                                   \
                int n = n0 + wave_n + (nidx_) * 32 + l31;                    \
                int cnt = __popc((unsigned)((bits >> (rr * 4)) & 0xFull));   \
                Out[(size_t)m * N + n] = 0.25f * (float)cnt;                 \
            }                                                                \
        } else {                                                             \
            const int kbase = (n0 + wave_n + (nidx_) * 32) >> 4;             \
            const ushort4v pk = *(const ushort4v*)&myt[(l31 * 2 + half) * 4];\
            _Pragma("unroll")                                                \
            for (int t = 0; t < TSTEPS; ++t) {                               \
                uint32_t m16 = pk[t];                                        \
                uint4 o;                                                     \
                o.x = (((m16      ) & 0xFu) * 0x00204081u & 0x01010101u) * 0x3Fu; \
                o.y = (((m16 >>  4) & 0xFu) * 0x00204081u & 0x01010101u) * 0x3Fu; \
                o.z = (((m16 >>  8) & 0xFu) * 0x00204081u & 0x01010101u) * 0x3Fu; \
                o.w = (((m16 >> 12) & 0xFu) * 0x00204081u & 0x01010101u) * 0x3Fu; \
                *(uint4*)(Sbytes + ((((size_t)m_blk * NKBo + kbase + half) * 4 + t) \
                                    * 32 + l31) * 16) = o;                   \
            }                                                                \
        }                                                                    \
    }

    EPILOG(acc0, 0);
    EPILOG(acc1, 1);

#undef EPILOG
}

// ---------------------------------------------------------------------------
// Zero out2 (graph-capture-safe replacement for hipMemsetAsync).
// ---------------------------------------------------------------------------
__global__ void zero_out2(float* __restrict__ out2, int n)
{
    int i = blockIdx.x * blockDim.x + threadIdx.x;
    if (i < n) out2[i] = 0.0f;
}

// ---------------------------------------------------------------------------
// out2[b][d] += partial sums over L (8 chunks of 64, atomic, EXACT: all
// values are multiples of 2^-11 with total <= 1 -> fp32 adds are exact and
// order-independent -> bitwise-equal to the reference mean).
// ---------------------------------------------------------------------------
__global__ void mean_over_L_atomic(const float* __restrict__ out,
                                   float* __restrict__ out2,
                                   int B, int L, int D)
{
    int id = blockIdx.x * blockDim.x + threadIdx.x;   // B*D*8
    int bd = id & (B * D - 1);
    int chunk = id >> 14;                             // B*D = 16384 = 2^14
    int b = bd >> 10, d = bd & (D - 1);               // D = 1024
    const float* p = out + (size_t)b * L * D + (size_t)chunk * 64 * D + d;
    float s = 0.0f;
#pragma unroll 8
    for (int l = 0; l < 64; ++l) s += p[(size_t)l * D];
    atomicAdd(out2 + bd, s * (1.0f / 512.0f));
}

// ---------------------------------------------------------------------------
extern "C" void kernel_launch(void* const* d_in, const int* in_sizes, int n_in,
                              void* d_out, int out_size, void* d_ws, size_t ws_size,
                              hipStream_t stream)
{
    const float* inputs  = (const float*)d_in[0];  // [16,512,128]
    const float* enc_W   = (const float*)d_in[1];  // [128,1024]
    const float* enc_b   = (const float*)d_in[2];  // [1024]
    const float* W_cells = (const float*)d_in[3];  // [2,1024,1024]
    const float* b_cells = (const float*)d_in[4];  // [2,1024]

    const int B = 16, L = 512, C = 128, D = 1024;
    const int M = B * L;  // 8192

    // ws: s1 i8 4MB | W1h/l 0.5MB | W2h/l 4MB | W3h/l 4MB | h0 32MB | h1 32MB
    char* ws = (char*)d_ws;
    size_t off = 0;
    uint8_t* s1 = (uint8_t*)(ws + off);
    off += (size_t)(M / 32) * (C / 16) * 4 * 32 * 16;
    bf16_t* W1h = (bf16_t*)(ws + off); off += (size_t)C * D * 2;
    bf16_t* W1l = (bf16_t*)(ws + off); off += (size_t)C * D * 2;
    bf16_t* W2h = (bf16_t*)(ws + off); off += (size_t)D * D * 2;
    bf16_t* W2l = (bf16_t*)(ws + off); off += (size_t)D * D * 2;
    bf16_t* W3h = (bf16_t*)(ws + off); off += (size_t)D * D * 2;
    bf16_t* W3l = (bf16_t*)(ws + off); off += (size_t)D * D * 2;
    uint8_t* h0 = (uint8_t*)(ws + off);
    off += (size_t)(M / 32) * (D / 16) * 4 * 32 * 16;
    uint8_t* h1 = (uint8_t*)(ws + off);

    float* out  = (float*)d_out;          // [M, D]
    float* out2 = out + (size_t)M * D;    // [B, D]

    split_transpose_all<<<dim3(32, 32, 3), 256, 0, stream>>>(
        enc_W, W_cells, W1h, W1l, W2h, W2l, W3h, W3l);

    spike_encode_i8<<<256, 256, 0, stream>>>(inputs, (uint4*)s1);

    zero_out2<<<(B * D + 255) / 256, 256, 0, stream>>>(out2, B * D);

    const int nblocks = (M / 64) * (D / 128);   // 1024
    gemm_lif_mfma<128, false><<<nblocks, 256, 0, stream>>>(
        s1, W1h, W1l, enc_b, h0, nullptr, M, D);
    gemm_lif_mfma<1024, false><<<nblocks, 256, 0, stream>>>(
        h0, W2h, W2l, b_cells, h1, nullptr, M, D);
    gemm_lif_mfma<1024, true><<<nblocks, 256, 0, stream>>>(
        h1, W3h, W3l, b_cells + D, nullptr, out, M, D);

    mean_over_L_atomic<<<(B * D * 8) / 256, 256, 0, stream>>>(
        out, out2, B, L, D);
}

// Round 5
// 318.913 us; speedup vs baseline: 1.0436x; 1.0436x over previous
//
#include <hip/hip_runtime.h>
#include <hip/hip_bf16.h>
#include <stdint.h>

#define TSTEPS 4

typedef __bf16 bf16_t;
typedef __attribute__((ext_vector_type(8))) __bf16 bf16x8;
typedef __attribute__((ext_vector_type(16))) float f32x16;
typedef __attribute__((ext_vector_type(4))) unsigned short ushort4v;

union frag_u { bf16x8 v; uint32_t d[4]; unsigned short u[8]; };

// gfx9 s_waitcnt immediates: vmcnt low4 [3:0] hi2 [15:14]; expcnt=7,lgkm=15 off
#define VMCNT12 0xF7C
#define VMCNT6  0xF76
#define VMCNT0  0xF70

// ---------------------------------------------------------------------------
// R21 = R18 structure (depth-3 prefetch, lb(256,3), XCD swizzle — the 118us
// config) + R19's 1-perm expansion (0x3F spike bytes -> high byte = bf16 0.5,
// B pre-doubled). R19 bundled this with lb(256,4) which squeezed VGPR 72->64
// and broke the prefetch scheduling; this round reverts ONLY that confound.
// A layout: [m_blk32][kb16][t][row0..31][16 bytes], byte = 0x00 / 0x3F.
// B-frag layout: packet ((n>>5)*NKB + (k>>4))*512 + ((n&31)+32*((k>>3)&1))*8
// + (k&7), bf16, value = 2*w_hi / 2*w_lo (exact exponent bump of the
// already-rounded hi/lo, so 0.5*(2w) = 1.0*w bitwise).
// ---------------------------------------------------------------------------

// ---------------------------------------------------------------------------
// Stage 1: input LIF encoder -> spike 0x3F bytes. C=128. XLA-exact LIF.
// ---------------------------------------------------------------------------
__global__ void spike_encode_i8(const float* __restrict__ x,
                                uint4* __restrict__ s1)
{
    const int C = 128;
    int tid = blockIdx.x * blockDim.x + threadIdx.x;  // 65536 = 256*8*32
    int row = tid & 31;
    int kb  = (tid >> 5) & 7;
    int m_blk = tid >> 8;
    int m = m_blk * 32 + row;
    const float* px = x + (size_t)m * C + kb * 16;
    float xv[16];
#pragma unroll
    for (int j = 0; j < 16; j += 4) {
        float4 t4 = *(const float4*)(px + j);
        xv[j] = t4.x; xv[j+1] = t4.y; xv[j+2] = t4.z; xv[j+3] = t4.w;
    }
    float v[16];
#pragma unroll
    for (int j = 0; j < 16; ++j) v[j] = 0.0f;
#pragma unroll
    for (int t = 0; t < TSTEPS; ++t) {
        uint32_t dw[4] = {0u, 0u, 0u, 0u};
#pragma unroll
        for (int j = 0; j < 16; ++j) {
            float vv = __fadd_rn(v[j], __fmul_rn(__fsub_rn(xv[j], v[j]), 0.5f));
            bool sp = (vv >= 1.0f);
            dw[j >> 2] |= sp ? (0x3Fu << ((j & 3) * 8)) : 0u;
            v[j] = sp ? 0.0f : vv;
        }
        uint4 o; o.x = dw[0]; o.y = dw[1]; o.z = dw[2]; o.w = dw[3];
        s1[((size_t)(m_blk * 8 + kb) * 4 + t) * 32 + row] = o;
    }
}

// ---------------------------------------------------------------------------
// Weight prep: W [K][N] fp32 -> 2*hi / 2*lo bf16 split in B-frag layout.
// hi/lo rounding UNCHANGED; doubling applied to the already-rounded bf16
// values (exact exponent increment, no re-rounding).
// ---------------------------------------------------------------------------
__global__ void split_transpose_all(const float* __restrict__ enc_W,
                                    const float* __restrict__ W_cells,
                                    bf16_t* __restrict__ W1h, bf16_t* __restrict__ W1l,
                                    bf16_t* __restrict__ W2h, bf16_t* __restrict__ W2l,
                                    bf16_t* __restrict__ W3h, bf16_t* __restrict__ W3l)
{
    const int N = 1024;
    const float* W;
    bf16_t *hi, *lo;
    int K;
    if (blockIdx.z == 0) {
        if (blockIdx.x >= 4) return;
        W = enc_W; hi = W1h; lo = W1l; K = 128;
    } else if (blockIdx.z == 1) {
        W = W_cells; hi = W2h; lo = W2l; K = 1024;
    } else {
        W = W_cells + (size_t)1024 * 1024; hi = W3h; lo = W3l; K = 1024;
    }
    const int NKB = K >> 4;
    __shared__ float tile[32][33];
    int k0 = blockIdx.x * 32, n0 = blockIdx.y * 32;
    int tx = threadIdx.x & 31, ty = threadIdx.x >> 5;
    for (int kk = ty; kk < 32; kk += 8)
        tile[kk][tx] = W[(size_t)(k0 + kk) * N + n0 + tx];
    __syncthreads();

    const int nn = tx;
    const int oc = ty;            // 0..7
    const int o2 = oc & 3;        // k-octet
    const bool isLo = (oc >> 2) != 0;
    const int kblk = (k0 >> 4) + (o2 >> 1);
    const int lane_in_packet = nn + 32 * (o2 & 1);

    frag_u f;
#pragma unroll
    for (int j = 0; j < 8; ++j) {
        float wv = tile[o2 * 8 + j][nn];
        bf16_t h = (bf16_t)wv;                          // original hi rounding
        bf16_t l = (bf16_t)(wv - (float)h);             // original lo rounding
        f.v[j] = isLo ? (bf16_t)(2.0f * (float)l)       // exact doubling
                      : (bf16_t)(2.0f * (float)h);
    }
    bf16_t* dst = (isLo ? lo : hi)
        + ((size_t)((n0 + nn) >> 5) * NKB + kblk) * 512 + lane_in_packet * 8;
    *(bf16x8*)dst = f.v;
}

// ---------------------------------------------------------------------------
// Fused MFMA GEMM + multistep LIF. R21: 1-perm expansion, XCD-locality
// swizzle, depth-3 register prefetch (vmcnt(12)), 3 blocks/CU (R18's
// occupancy — the lb(256,4) squeeze was R19's regression).
// ---------------------------------------------------------------------------
template <int K, bool LAST>
__global__ __launch_bounds__(256, 3)
void gemm_lif_mfma(const uint8_t* __restrict__ Abytes,
                   const bf16_t* __restrict__ Bh,
                   const bf16_t* __restrict__ Bl,
                   const float* __restrict__ bias,
                   uint8_t* __restrict__ Sbytes,
                   float* __restrict__ Out,
                   int M, int N)
{
    constexpr int NKB = K >> 4;                 // 8 or 64 (multiple of 4)
    __shared__ __align__(8) unsigned short sh[4][256];   // [wave][row][kb][t]

    const int tid = threadIdx.x;
    const int lane = tid & 63;
    const int wid = tid >> 6;
    const int l31 = lane & 31;
    const int half = lane >> 5;

    // XCD-locality swizzle: 2048 blocks, default XCD = bid & 7.
    // XCD x owns m_t in [x*16, x*16+16). Within an XCD, walk
    // nh(2) x mloc(16) x n8(8): hot set = A-tile (256KB i8) + 8 B-panels
    // (2MB) < 4MB per-XCD L2. Bijective: bid -> (m_t, n_t).
    const int bid = blockIdx.x;
    const int xcd = bid & 7;
    const int j   = bid >> 3;                   // 0..255
    const int nh   = j >> 7;                    // 0..1
    const int r    = j & 127;
    const int mloc = r >> 3;                    // 0..15
    const int n_t  = nh * 8 + (r & 7);          // 0..15
    const int m_t  = xcd * 16 + mloc;           // 0..127

    const int m0 = m_t * 64, n0 = n_t * 64;
    const int wave_m = (wid & 1) * 32;
    const int wave_n = (wid >> 1) * 32;
    const int m_blk = (m0 + wave_m) >> 5;
    const int n_blk = (n0 + wave_n) >> 5;

    const uint8_t* pA = Abytes + (size_t)m_blk * NKB * 4 * 512 + l31 * 16 + half * 8;
    const bf16_t* pH = Bh + (size_t)n_blk * NKB * 512 + lane * 8;
    const bf16_t* pL = Bl + (size_t)n_blk * NKB * 512 + lane * 8;

    f32x16 acc[TSTEPS];
#pragma unroll
    for (int t = 0; t < TSTEPS; ++t)
        for (int rr = 0; rr < 16; ++rr) acc[t][rr] = 0.0f;

    uint2 fm[4][4];
    bf16x8 fh[4], fl[4];

#define LOADB(kb_, s_) {                                                     \
        fm[s_][0] = *(const uint2*)(pA + ((size_t)(kb_) * 4 + 0) * 512);     \
        fm[s_][1] = *(const uint2*)(pA + ((size_t)(kb_) * 4 + 1) * 512);     \
        fm[s_][2] = *(const uint2*)(pA + ((size_t)(kb_) * 4 + 2) * 512);     \
        fm[s_][3] = *(const uint2*)(pA + ((size_t)(kb_) * 4 + 3) * 512);     \
        fh[s_] = *(const bf16x8*)(pH + (kb_) * 512);                         \
        fl[s_] = *(const bf16x8*)(pL + (kb_) * 512);                         \
    }

// byte 0x3F -> high byte of each 16-bit half = 0x3F00 = bf16 0.5 (1 perm/dw)
#define EXPANDF(a_, f_) {                                                    \
        (f_).d[0] = __builtin_amdgcn_perm((a_).x, 0u, 0x05000400u);          \
        (f_).d[1] = __builtin_amdgcn_perm((a_).x, 0u, 0x07000600u);          \
        (f_).d[2] = __builtin_amdgcn_perm((a_).y, 0u, 0x05000400u);          \
        (f_).d[3] = __builtin_amdgcn_perm((a_).y, 0u, 0x07000600u);          \
    }

#define MFMASTEP(s_) {                                                       \
        frag_u af0, af1, af2, af3;                                           \
        EXPANDF(fm[s_][0], af0);                                             \
        EXPANDF(fm[s_][1], af1);                                             \
        EXPANDF(fm[s_][2], af2);                                             \
        EXPANDF(fm[s_][3], af3);                                             \
        acc[0] = __builtin_amdgcn_mfma_f32_32x32x16_bf16(af0.v, fh[s_], acc[0], 0, 0, 0); \
        acc[1] = __builtin_amdgcn_mfma_f32_32x32x16_bf16(af1.v, fh[s_], acc[1], 0, 0, 0); \
        acc[2] = __builtin_amdgcn_mfma_f32_32x32x16_bf16(af2.v, fh[s_], acc[2], 0, 0, 0); \
        acc[3] = __builtin_amdgcn_mfma_f32_32x32x16_bf16(af3.v, fh[s_], acc[3], 0, 0, 0); \
        acc[0] = __builtin_amdgcn_mfma_f32_32x32x16_bf16(af0.v, fl[s_], acc[0], 0, 0, 0); \
        acc[1] = __builtin_amdgcn_mfma_f32_32x32x16_bf16(af1.v, fl[s_], acc[1], 0, 0, 0); \
        acc[2] = __builtin_amdgcn_mfma_f32_32x32x16_bf16(af2.v, fl[s_], acc[2], 0, 0, 0); \
        acc[3] = __builtin_amdgcn_mfma_f32_32x32x16_bf16(af3.v, fl[s_], acc[3], 0, 0, 0); \
    }

// steady-state: prefetch kb_+2 into slot (s_+2)&3, wait for kb_'s loads
#define STEPP(kb_, s_) {                                                     \
        LOADB((kb_) + 2, ((s_) + 2) & 3);                                    \
        __builtin_amdgcn_s_waitcnt(VMCNT12);                                 \
        asm volatile("" ::: "memory");                                       \
        MFMASTEP(s_);                                                        \
    }
// drain steps (no more prefetch)
#define STEPW(s_, w_) {                                                      \
        __builtin_amdgcn_s_waitcnt(w_);                                      \
        asm volatile("" ::: "memory");                                       \
        MFMASTEP(s_);                                                        \
    }

    LOADB(0, 0);
    LOADB(1, 1);
    for (int kb = 0; kb < NKB - 4; kb += 4) {
        STEPP(kb + 0, 0);
        STEPP(kb + 1, 1);
        STEPP(kb + 2, 2);
        STEPP(kb + 3, 3);
    }
    STEPP(NKB - 4, 0);          // prefetch NKB-2
    STEPP(NKB - 3, 1);          // prefetch NKB-1
    STEPW(2, VMCNT6);           // kb = NKB-2
    STEPW(3, VMCNT0);           // kb = NKB-1

#undef STEPW
#undef STEPP
#undef MFMASTEP
#undef EXPANDF
#undef LOADB

    // --- LIF epilogue: t-scan in registers (XLA-exact arithmetic) ---
    const float bv = bias[n0 + wave_n + l31];
    f32x16 vmem;
#pragma unroll
    for (int rr = 0; rr < 16; ++rr) vmem[rr] = 0.0f;
    uint64_t bits = 0ull;
    unsigned short* myt = &sh[wid][0];          // [row][kb][t] = [32][2][4]

    const int NKBo = N >> 4;
    const int kbase = (n0 + wave_n) >> 4;

    for (int t = 0; t < TSTEPS; ++t) {
#pragma unroll
        for (int rr = 0; rr < 16; ++rr) {
            float y = __fadd_rn(acc[t][rr], bv);
            float vv = vmem[rr];
            vv = __fadd_rn(vv, __fmul_rn(__fsub_rn(y, vv), 0.5f));
            bool sp = (vv >= 1.0f);
            vmem[rr] = sp ? 0.0f : vv;
            if (LAST) {
                bits |= sp ? (1ull << (rr * 4 + t)) : 0ull;
            } else {
                unsigned long long b = __ballot(sp);
                if (l31 == 0) {
                    uint32_t hb = (uint32_t)(b >> (half * 32));
                    int rowi = (rr & 3) + 8 * (rr >> 2) + 4 * half;
                    myt[(rowi * 2 + 0) * 4 + t] = (unsigned short)hb;
                    myt[(rowi * 2 + 1) * 4 + t] = (unsigned short)(hb >> 16);
                }
            }
        }
    }

    if (LAST) {
#pragma unroll
        for (int rr = 0; rr < 16; ++rr) {
            int m_r = (rr & 3) + 8 * (rr >> 2) + 4 * half;
            int m = m0 + wave_m + m_r;
            int n = n0 + wave_n + l31;
            int cnt = __popc((unsigned)((bits >> (rr * 4)) & 0xFull));
            Out[(size_t)m * N + n] = 0.25f * (float)cnt;
        }
    } else {
        // Emit next-stage A bytes: 0x00 / 0x3F.
        const ushort4v pk = *(const ushort4v*)&myt[(l31 * 2 + half) * 4];
#pragma unroll
        for (int t = 0; t < TSTEPS; ++t) {
            uint32_t m16 = pk[t];
            uint4 o;
            o.x = (((m16      ) & 0xFu) * 0x00204081u & 0x01010101u) * 0x3Fu;
            o.y = (((m16 >>  4) & 0xFu) * 0x00204081u & 0x01010101u) * 0x3Fu;
            o.z = (((m16 >>  8) & 0xFu) * 0x00204081u & 0x01010101u) * 0x3Fu;
            o.w = (((m16 >> 12) & 0xFu) * 0x00204081u & 0x01010101u) * 0x3Fu;
            *(uint4*)(Sbytes + ((((size_t)m_blk * NKBo + kbase + half) * 4 + t)
                                * 32 + l31) * 16) = o;
        }
    }
}

// ---------------------------------------------------------------------------
// Zero out2 (graph-capture-safe replacement for hipMemsetAsync).
// ---------------------------------------------------------------------------
__global__ void zero_out2(float* __restrict__ out2, int n)
{
    int i = blockIdx.x * blockDim.x + threadIdx.x;
    if (i < n) out2[i] = 0.0f;
}

// ---------------------------------------------------------------------------
// out2[b][d] += partial sums over L (8 chunks of 64, atomic, EXACT: all
// values are multiples of 2^-11 with total <= 1 -> fp32 adds are exact and
// order-independent -> bitwise-equal to the reference mean).
// ---------------------------------------------------------------------------
__global__ void mean_over_L_atomic(const float* __restrict__ out,
                                   float* __restrict__ out2,
                                   int B, int L, int D)
{
    int id = blockIdx.x * blockDim.x + threadIdx.x;   // B*D*8
    int bd = id & (B * D - 1);
    int chunk = id >> 14;                             // B*D = 16384 = 2^14
    int b = bd >> 10, d = bd & (D - 1);               // D = 1024
    const float* p = out + (size_t)b * L * D + (size_t)chunk * 64 * D + d;
    float s = 0.0f;
#pragma unroll 8
    for (int l = 0; l < 64; ++l) s += p[(size_t)l * D];
    atomicAdd(out2 + bd, s * (1.0f / 512.0f));
}

// ---------------------------------------------------------------------------
extern "C" void kernel_launch(void* const* d_in, const int* in_sizes, int n_in,
                              void* d_out, int out_size, void* d_ws, size_t ws_size,
                              hipStream_t stream)
{
    const float* inputs  = (const float*)d_in[0];  // [16,512,128]
    const float* enc_W   = (const float*)d_in[1];  // [128,1024]
    const float* enc_b   = (const float*)d_in[2];  // [1024]
    const float* W_cells = (const float*)d_in[3];  // [2,1024,1024]
    const float* b_cells = (const float*)d_in[4];  // [2,1024]

    const int B = 16, L = 512, C = 128, D = 1024;
    const int M = B * L;  // 8192

    // ws: s1 i8 4MB | W1h/l 0.5MB | W2h/l 4MB | W3h/l 4MB | h0 32MB | h1 32MB
    char* ws = (char*)d_ws;
    size_t off = 0;
    uint8_t* s1 = (uint8_t*)(ws + off);
    off += (size_t)(M / 32) * (C / 16) * 4 * 32 * 16;
    bf16_t* W1h = (bf16_t*)(ws + off); off += (size_t)C * D * 2;
    bf16_t* W1l = (bf16_t*)(ws + off); off += (size_t)C * D * 2;
    bf16_t* W2h = (bf16_t*)(ws + off); off += (size_t)D * D * 2;
    bf16_t* W2l = (bf16_t*)(ws + off); off += (size_t)D * D * 2;
    bf16_t* W3h = (bf16_t*)(ws + off); off += (size_t)D * D * 2;
    bf16_t* W3l = (bf16_t*)(ws + off); off += (size_t)D * D * 2;
    uint8_t* h0 = (uint8_t*)(ws + off);
    off += (size_t)(M / 32) * (D / 16) * 4 * 32 * 16;
    uint8_t* h1 = (uint8_t*)(ws + off);

    float* out  = (float*)d_out;          // [M, D]
    float* out2 = out + (size_t)M * D;    // [B, D]

    split_transpose_all<<<dim3(32, 32, 3), 256, 0, stream>>>(
        enc_W, W_cells, W1h, W1l, W2h, W2l, W3h, W3l);

    spike_encode_i8<<<256, 256, 0, stream>>>(inputs, (uint4*)s1);

    zero_out2<<<(B * D + 255) / 256, 256, 0, stream>>>(out2, B * D);

    const int nblocks = (M / 64) * (D / 64);   // 2048
    gemm_lif_mfma<128, false><<<nblocks, 256, 0, stream>>>(
        s1, W1h, W1l, enc_b, h0, nullptr, M, D);
    gemm_lif_mfma<1024, false><<<nblocks, 256, 0, stream>>>(
        h0, W2h, W2l, b_cells, h1, nullptr, M, D);
    gemm_lif_mfma<1024, true><<<nblocks, 256, 0, stream>>>(
        h1, W3h, W3l, b_cells + D, nullptr, out, M, D);

    mean_over_L_atomic<<<(B * D * 8) / 256, 256, 0, stream>>>(
        out, out2, B, L, D);
}

// Round 6
// 317.093 us; speedup vs baseline: 1.0495x; 1.0057x over previous
//
#include <hip/hip_runtime.h>
#include <hip/hip_bf16.h>
#include <stdint.h>

#define TSTEPS 4

typedef __bf16 bf16_t;
typedef __attribute__((ext_vector_type(8))) __bf16 bf16x8;
typedef __attribute__((ext_vector_type(16))) float f32x16;
typedef __attribute__((ext_vector_type(4))) unsigned short ushort4v;

union frag_u { bf16x8 v; uint32_t d[4]; unsigned short u[8]; };

// gfx9 s_waitcnt immediates: vmcnt low4 [3:0]; exp [6:4]; lgkm [11:8].
#define WT_VM5_LG0  0x075   // vmcnt(5)  lgkmcnt(0)  : A(kb) done + ds_reads done
#define WT_VM4      0xF74   // vmcnt(4)             : stage(kb+1) landed in LDS
#define WT_VM0_LG0  0x070   // full drain (tail)

// ---------------------------------------------------------------------------
// R22: LDS-staged B (the L1-line dedup). Model: every VMEM byte transits the
// CU L1 return port (~128B/cyc); R16/R18/R21 all plateau at 47-50% MfmaUtil
// = 192 matrix-cyc / 384 L1-cyc per CU window (64 lines per 8-MFMA wave-step).
// B is read twice per block (2 waves share n_blk) -> stage it once per block
// per kb via global_load_lds (4x1KB chunks, one per wave, lane-linear), read
// back via ds_read_b128. A stays register-direct (depth-1, 2 slots). Lines:
// A 16x32 + B 4x64 = 768 per 16-wave window /2 = 384 cyc vs 256 matrix ->
// ceiling 67% (was 50%). VGPR drops (no B reg pipeline) -> 4 blocks/CU.
// Spike bytes 0x3F -> v_perm high-byte = bf16 0.5; B pre-doubled (exact
// exponent bump) so products are bitwise 1.0*w (R19/R21-proven, absmax 0).
// A layout: [m_blk32][kb16][t][row0..31][16 bytes], byte = 0x00 / 0x3F.
// B-frag layout: packet ((n>>5)*NKB + (k>>4))*512 + ((n&31)+32*((k>>3)&1))*8
// + (k&7), bf16, value = 2*w_hi / 2*w_lo.
// ---------------------------------------------------------------------------

// ---------------------------------------------------------------------------
// Stage 1: input LIF encoder -> spike 0x3F bytes. C=128. XLA-exact LIF.
// ---------------------------------------------------------------------------
__global__ void spike_encode_i8(const float* __restrict__ x,
                                uint4* __restrict__ s1)
{
    const int C = 128;
    int tid = blockIdx.x * blockDim.x + threadIdx.x;  // 65536 = 256*8*32
    int row = tid & 31;
    int kb  = (tid >> 5) & 7;
    int m_blk = tid >> 8;
    int m = m_blk * 32 + row;
    const float* px = x + (size_t)m * C + kb * 16;
    float xv[16];
#pragma unroll
    for (int j = 0; j < 16; j += 4) {
        float4 t4 = *(const float4*)(px + j);
        xv[j] = t4.x; xv[j+1] = t4.y; xv[j+2] = t4.z; xv[j+3] = t4.w;
    }
    float v[16];
#pragma unroll
    for (int j = 0; j < 16; ++j) v[j] = 0.0f;
#pragma unroll
    for (int t = 0; t < TSTEPS; ++t) {
        uint32_t dw[4] = {0u, 0u, 0u, 0u};
#pragma unroll
        for (int j = 0; j < 16; ++j) {
            float vv = __fadd_rn(v[j], __fmul_rn(__fsub_rn(xv[j], v[j]), 0.5f));
            bool sp = (vv >= 1.0f);
            dw[j >> 2] |= sp ? (0x3Fu << ((j & 3) * 8)) : 0u;
            v[j] = sp ? 0.0f : vv;
        }
        uint4 o; o.x = dw[0]; o.y = dw[1]; o.z = dw[2]; o.w = dw[3];
        s1[((size_t)(m_blk * 8 + kb) * 4 + t) * 32 + row] = o;
    }
}

// ---------------------------------------------------------------------------
// Weight prep: W [K][N] fp32 -> 2*hi / 2*lo bf16 split in B-frag layout.
// ---------------------------------------------------------------------------
__global__ void split_transpose_all(const float* __restrict__ enc_W,
                                    const float* __restrict__ W_cells,
                                    bf16_t* __restrict__ W1h, bf16_t* __restrict__ W1l,
                                    bf16_t* __restrict__ W2h, bf16_t* __restrict__ W2l,
                                    bf16_t* __restrict__ W3h, bf16_t* __restrict__ W3l)
{
    const int N = 1024;
    const float* W;
    bf16_t *hi, *lo;
    int K;
    if (blockIdx.z == 0) {
        if (blockIdx.x >= 4) return;
        W = enc_W; hi = W1h; lo = W1l; K = 128;
    } else if (blockIdx.z == 1) {
        W = W_cells; hi = W2h; lo = W2l; K = 1024;
    } else {
        W = W_cells + (size_t)1024 * 1024; hi = W3h; lo = W3l; K = 1024;
    }
    const int NKB = K >> 4;
    __shared__ float tile[32][33];
    int k0 = blockIdx.x * 32, n0 = blockIdx.y * 32;
    int tx = threadIdx.x & 31, ty = threadIdx.x >> 5;
    for (int kk = ty; kk < 32; kk += 8)
        tile[kk][tx] = W[(size_t)(k0 + kk) * N + n0 + tx];
    __syncthreads();

    const int nn = tx;
    const int oc = ty;            // 0..7
    const int o2 = oc & 3;        // k-octet
    const bool isLo = (oc >> 2) != 0;
    const int kblk = (k0 >> 4) + (o2 >> 1);
    const int lane_in_packet = nn + 32 * (o2 & 1);

    frag_u f;
#pragma unroll
    for (int j = 0; j < 8; ++j) {
        float wv = tile[o2 * 8 + j][nn];
        bf16_t h = (bf16_t)wv;                          // original hi rounding
        bf16_t l = (bf16_t)(wv - (float)h);             // original lo rounding
        f.v[j] = isLo ? (bf16_t)(2.0f * (float)l)       // exact doubling
                      : (bf16_t)(2.0f * (float)h);
    }
    bf16_t* dst = (isLo ? lo : hi)
        + ((size_t)((n0 + nn) >> 5) * NKB + kblk) * 512 + lane_in_packet * 8;
    *(bf16x8*)dst = f.v;
}

// ---------------------------------------------------------------------------
// Fused MFMA GEMM + multistep LIF. R22: LDS-staged B (global_load_lds,
// 2-phase, counted waits), register-direct A depth-1, XCD swizzle,
// 4 blocks/CU.
// ---------------------------------------------------------------------------
template <int K, bool LAST>
__global__ __launch_bounds__(256, 4)
void gemm_lif_mfma(const uint8_t* __restrict__ Abytes,
                   const bf16_t* __restrict__ Bh,
                   const bf16_t* __restrict__ Bl,
                   const float* __restrict__ bias,
                   uint8_t* __restrict__ Sbytes,
                   float* __restrict__ Out,
                   int M, int N)
{
    constexpr int NKB = K >> 4;                 // 8 or 64 (even)
    __shared__ __align__(16) uint8_t ldsB[2][4096];      // dbuf B kb-slab
    __shared__ __align__(8) unsigned short sh[4][256];   // epilogue, per-wave

    const int tid = threadIdx.x;
    const int lane = tid & 63;
    const int wid = tid >> 6;
    const int l31 = lane & 31;
    const int half = lane >> 5;

    // XCD-locality swizzle (unchanged from R18): XCD x owns m_t in
    // [x*16, x*16+16); walk nh(2) x mloc(16) x n8(8). Bijective.
    const int bid = blockIdx.x;
    const int xcd = bid & 7;
    const int j   = bid >> 3;                   // 0..255
    const int nh   = j >> 7;                    // 0..1
    const int r    = j & 127;
    const int mloc = r >> 3;                    // 0..15
    const int n_t  = nh * 8 + (r & 7);          // 0..15
    const int m_t  = xcd * 16 + mloc;           // 0..127

    const int m0 = m_t * 64, n0 = n_t * 64;
    const int wave_m = (wid & 1) * 32;
    const int wave_n = (wid >> 1) * 32;
    const int m_blk = (m0 + wave_m) >> 5;
    const int n_blk = (n0 + wave_n) >> 5;

    const uint8_t* pA = Abytes + (size_t)m_blk * NKB * 4 * 512 + l31 * 16 + half * 8;

    // B staging: wave wid stages chunk wid = (n_local = wid>>1, plane = wid&1)
    // at LDS offset wid*1024. Source is the 1KB lane-linear packet.
    const uint8_t* stage_src = (const uint8_t*)(((wid & 1) ? Bl : Bh)
        + (size_t)((n0 >> 5) + (wid >> 1)) * NKB * 512) + (lane << 4);
    // Consumer: wave wid reads n_local = wid>>1: hi at +0, lo at +1024.
    const uint8_t* ldsRd = &ldsB[0][0] + ((wid >> 1) << 11) + (lane << 4);

    f32x16 acc[TSTEPS];
#pragma unroll
    for (int t = 0; t < TSTEPS; ++t)
        for (int rr = 0; rr < 16; ++rr) acc[t][rr] = 0.0f;

    uint2 fm[2][4];

#define STAGE(kb_, b_)                                                        \
    __builtin_amdgcn_global_load_lds(                                         \
        (const __attribute__((address_space(1))) uint32_t*)                   \
            (stage_src + (size_t)(kb_) * 1024),                               \
        (__attribute__((address_space(3))) uint32_t*)(&ldsB[b_][wid << 10]),  \
        16, 0, 0);

#define LOADA(kb_, s_) {                                                     \
        fm[s_][0] = *(const uint2*)(pA + ((size_t)(kb_) * 4 + 0) * 512);     \
        fm[s_][1] = *(const uint2*)(pA + ((size_t)(kb_) * 4 + 1) * 512);     \
        fm[s_][2] = *(const uint2*)(pA + ((size_t)(kb_) * 4 + 2) * 512);     \
        fm[s_][3] = *(const uint2*)(pA + ((size_t)(kb_) * 4 + 3) * 512);     \
    }

// byte 0x3F -> high byte of each 16-bit half = 0x3F00 = bf16 0.5 (1 perm/dw)
#define EXPANDF(a_, f_) {                                                    \
        (f_).d[0] = __builtin_amdgcn_perm((a_).x, 0u, 0x05000400u);          \
        (f_).d[1] = __builtin_amdgcn_perm((a_).x, 0u, 0x07000600u);          \
        (f_).d[2] = __builtin_amdgcn_perm((a_).y, 0u, 0x05000400u);          \
        (f_).d[3] = __builtin_amdgcn_perm((a_).y, 0u, 0x07000600u);          \
    }

#define MFMAS(s_, fhv_, flv_) {                                              \
        frag_u af0, af1, af2, af3;                                           \
        EXPANDF(fm[s_][0], af0);                                             \
        EXPANDF(fm[s_][1], af1);                                             \
        EXPANDF(fm[s_][2], af2);                                             \
        EXPANDF(fm[s_][3], af3);                                             \
        acc[0] = __builtin_amdgcn_mfma_f32_32x32x16_bf16(af0.v, fhv_, acc[0], 0, 0, 0); \
        acc[1] = __builtin_amdgcn_mfma_f32_32x32x16_bf16(af1.v, fhv_, acc[1], 0, 0, 0); \
        acc[2] = __builtin_amdgcn_mfma_f32_32x32x16_bf16(af2.v, fhv_, acc[2], 0, 0, 0); \
        acc[3] = __builtin_amdgcn_mfma_f32_32x32x16_bf16(af3.v, fhv_, acc[3], 0, 0, 0); \
        acc[0] = __builtin_amdgcn_mfma_f32_32x32x16_bf16(af0.v, flv_, acc[0], 0, 0, 0); \
        acc[1] = __builtin_amdgcn_mfma_f32_32x32x16_bf16(af1.v, flv_, acc[1], 0, 0, 0); \
        acc[2] = __builtin_amdgcn_mfma_f32_32x32x16_bf16(af2.v, flv_, acc[2], 0, 0, 0); \
        acc[3] = __builtin_amdgcn_mfma_f32_32x32x16_bf16(af3.v, flv_, acc[3], 0, 0, 0); \
    }

// Uniform step: compute kb (parity p = kb&1, A slot p, B buf p), while
// staging kb+1 into buf p^1 and loading A(kb+1) into slot p^1.
// vmcnt(5)+lgkm(0) before MFMA: outstanding = [A(kb+1) is 4 youngest +
// stage(kb+1) 1] -> A(kb) guaranteed done; ds_reads drained by lgkm(0).
// vmcnt(4) before barrier: stage(kb+1) landed (A(kb+1) 4 may remain).
#define STEP(kb_, p_) {                                                      \
        STAGE((kb_) + 1, (p_) ^ 1);                                          \
        LOADA((kb_) + 1, (p_) ^ 1);                                          \
        bf16x8 fhv = *(const bf16x8*)(ldsRd + (p_) * 4096);                  \
        bf16x8 flv = *(const bf16x8*)(ldsRd + (p_) * 4096 + 1024);           \
        __builtin_amdgcn_s_waitcnt(WT_VM5_LG0);                              \
        asm volatile("" ::: "memory");                                       \
        MFMAS(p_, fhv, flv);                                                 \
        __builtin_amdgcn_s_waitcnt(WT_VM4);                                  \
        asm volatile("" ::: "memory");                                       \
        __builtin_amdgcn_s_barrier();                                        \
        asm volatile("" ::: "memory");                                       \
    }

    // Prologue: stage kb=0 into buf0, A(0) into slot0.
    STAGE(0, 0);
    LOADA(0, 0);
    __builtin_amdgcn_s_waitcnt(WT_VM4);   // stage(0) done (A(0) 4 younger)
    asm volatile("" ::: "memory");
    __builtin_amdgcn_s_barrier();
    asm volatile("" ::: "memory");

    for (int kb = 0; kb < NKB - 2; kb += 2) {
        STEP(kb + 0, 0);
        STEP(kb + 1, 1);
    }
    STEP(NKB - 2, 0);                     // stages+loads NKB-1 (both valid)
    {   // final step kb = NKB-1 (parity 1): nothing left to issue
        bf16x8 fhv = *(const bf16x8*)(ldsRd + 4096);
        bf16x8 flv = *(const bf16x8*)(ldsRd + 4096 + 1024);
        __builtin_amdgcn_s_waitcnt(WT_VM0_LG0);
        asm volatile("" ::: "memory");
        MFMAS(1, fhv, flv);
    }

#undef STEP
#undef MFMAS
#undef EXPANDF
#undef LOADA
#undef STAGE

    // --- LIF epilogue: t-scan in registers (XLA-exact arithmetic) ---
    const float bv = bias[n0 + wave_n + l31];
    f32x16 vmem;
#pragma unroll
    for (int rr = 0; rr < 16; ++rr) vmem[rr] = 0.0f;
    uint64_t bits = 0ull;
    unsigned short* myt = &sh[wid][0];          // [row][kb][t] = [32][2][4]

    const int NKBo = N >> 4;
    const int kbase = (n0 + wave_n) >> 4;

    for (int t = 0; t < TSTEPS; ++t) {
#pragma unroll
        for (int rr = 0; rr < 16; ++rr) {
            float y = __fadd_rn(acc[t][rr], bv);
            float vv = vmem[rr];
            vv = __fadd_rn(vv, __fmul_rn(__fsub_rn(y, vv), 0.5f));
            bool sp = (vv >= 1.0f);
            vmem[rr] = sp ? 0.0f : vv;
            if (LAST) {
                bits |= sp ? (1ull << (rr * 4 + t)) : 0ull;
            } else {
                unsigned long long b = __ballot(sp);
                if (l31 == 0) {
                    uint32_t hb = (uint32_t)(b >> (half * 32));
                    int rowi = (rr & 3) + 8 * (rr >> 2) + 4 * half;
                    myt[(rowi * 2 + 0) * 4 + t] = (unsigned short)hb;
                    myt[(rowi * 2 + 1) * 4 + t] = (unsigned short)(hb >> 16);
                }
            }
        }
    }

    if (LAST) {
#pragma unroll
        for (int rr = 0; rr < 16; ++rr) {
            int m_r = (rr & 3) + 8 * (rr >> 2) + 4 * half;
            int m = m0 + wave_m + m_r;
            int n = n0 + wave_n + l31;
            int cnt = __popc((unsigned)((bits >> (rr * 4)) & 0xFull));
            Out[(size_t)m * N + n] = 0.25f * (float)cnt;
        }
    } else {
        // Emit next-stage A bytes: 0x00 / 0x3F.
        const ushort4v pk = *(const ushort4v*)&myt[(l31 * 2 + half) * 4];
#pragma unroll
        for (int t = 0; t < TSTEPS; ++t) {
            uint32_t m16 = pk[t];
            uint4 o;
            o.x = (((m16      ) & 0xFu) * 0x00204081u & 0x01010101u) * 0x3Fu;
            o.y = (((m16 >>  4) & 0xFu) * 0x00204081u & 0x01010101u) * 0x3Fu;
            o.z = (((m16 >>  8) & 0xFu) * 0x00204081u & 0x01010101u) * 0x3Fu;
            o.w = (((m16 >> 12) & 0xFu) * 0x00204081u & 0x01010101u) * 0x3Fu;
            *(uint4*)(Sbytes + ((((size_t)m_blk * NKBo + kbase + half) * 4 + t)
                                * 32 + l31) * 16) = o;
        }
    }
}

// ---------------------------------------------------------------------------
// Zero out2 (graph-capture-safe replacement for hipMemsetAsync).
// ---------------------------------------------------------------------------
__global__ void zero_out2(float* __restrict__ out2, int n)
{
    int i = blockIdx.x * blockDim.x + threadIdx.x;
    if (i < n) out2[i] = 0.0f;
}

// ---------------------------------------------------------------------------
// out2[b][d] += partial sums over L (8 chunks of 64, atomic, EXACT).
// ---------------------------------------------------------------------------
__global__ void mean_over_L_atomic(const float* __restrict__ out,
                                   float* __restrict__ out2,
                                   int B, int L, int D)
{
    int id = blockIdx.x * blockDim.x + threadIdx.x;   // B*D*8
    int bd = id & (B * D - 1);
    int chunk = id >> 14;                             // B*D = 16384 = 2^14
    int b = bd >> 10, d = bd & (D - 1);               // D = 1024
    const float* p = out + (size_t)b * L * D + (size_t)chunk * 64 * D + d;
    float s = 0.0f;
#pragma unroll 8
    for (int l = 0; l < 64; ++l) s += p[(size_t)l * D];
    atomicAdd(out2 + bd, s * (1.0f / 512.0f));
}

// ---------------------------------------------------------------------------
extern "C" void kernel_launch(void* const* d_in, const int* in_sizes, int n_in,
                              void* d_out, int out_size, void* d_ws, size_t ws_size,
                              hipStream_t stream)
{
    const float* inputs  = (const float*)d_in[0];  // [16,512,128]
    const float* enc_W   = (const float*)d_in[1];  // [128,1024]
    const float* enc_b   = (const float*)d_in[2];  // [1024]
    const float* W_cells = (const float*)d_in[3];  // [2,1024,1024]
    const float* b_cells = (const float*)d_in[4];  // [2,1024]

    const int B = 16, L = 512, C = 128, D = 1024;
    const int M = B * L;  // 8192

    // ws: s1 i8 4MB | W1h/l 0.5MB | W2h/l 4MB | W3h/l 4MB | h0 32MB | h1 32MB
    char* ws = (char*)d_ws;
    size_t off = 0;
    uint8_t* s1 = (uint8_t*)(ws + off);
    off += (size_t)(M / 32) * (C / 16) * 4 * 32 * 16;
    bf16_t* W1h = (bf16_t*)(ws + off); off += (size_t)C * D * 2;
    bf16_t* W1l = (bf16_t*)(ws + off); off += (size_t)C * D * 2;
    bf16_t* W2h = (bf16_t*)(ws + off); off += (size_t)D * D * 2;
    bf16_t* W2l = (bf16_t*)(ws + off); off += (size_t)D * D * 2;
    bf16_t* W3h = (bf16_t*)(ws + off); off += (size_t)D * D * 2;
    bf16_t* W3l = (bf16_t*)(ws + off); off += (size_t)D * D * 2;
    uint8_t* h0 = (uint8_t*)(ws + off);
    off += (size_t)(M / 32) * (D / 16) * 4 * 32 * 16;
    uint8_t* h1 = (uint8_t*)(ws + off);

    float* out  = (float*)d_out;          // [M, D]
    float* out2 = out + (size_t)M * D;    // [B, D]

    split_transpose_all<<<dim3(32, 32, 3), 256, 0, stream>>>(
        enc_W, W_cells, W1h, W1l, W2h, W2l, W3h, W3l);

    spike_encode_i8<<<256, 256, 0, stream>>>(inputs, (uint4*)s1);

    zero_out2<<<(B * D + 255) / 256, 256, 0, stream>>>(out2, B * D);

    const int nblocks = (M / 64) * (D / 64);   // 2048
    gemm_lif_mfma<128, false><<<nblocks, 256, 0, stream>>>(
        s1, W1h, W1l, enc_b, h0, nullptr, M, D);
    gemm_lif_mfma<1024, false><<<nblocks, 256, 0, stream>>>(
        h0, W2h, W2l, b_cells, h1, nullptr, M, D);
    gemm_lif_mfma<1024, true><<<nblocks, 256, 0, stream>>>(
        h1, W3h, W3l, b_cells + D, nullptr, out, M, D);

    mean_over_L_atomic<<<(B * D * 8) / 256, 256, 0, stream>>>(
        out, out2, B, L, D);
}